// Round 8
// baseline (2562.858 us; speedup 1.0000x reference)
//
#include <hip/hip_runtime.h>
#include <stdint.h>

#define B_ 2
#define E_ 8
#define N_ 1024
#define D_ 1024
#define H_ 4096

typedef float f32x4 __attribute__((ext_vector_type(4)));
typedef __bf16 bf16x8 __attribute__((ext_vector_type(8)));
typedef __attribute__((address_space(3))) const unsigned short lds_cus;

__device__ __forceinline__ unsigned short f2bf(float f) {
  union { float f; uint32_t u; } v; v.f = f;
  uint32_t u = v.u;
  return (unsigned short)((u + 0x7FFFu + ((u >> 16) & 1u)) >> 16);  // RNE
}

// tanh-form GELU (max |delta| vs exact erf-GELU ~1e-3, inside threshold headroom)
__device__ __forceinline__ float gelu_fast(float x) {
  float x3 = x * x * x;
  float y = 0.79788456080286536f * (x + 0.044715f * x3);
  float e = __expf(2.0f * y);
  float t = 1.0f - 2.0f / (e + 1.0f);   // tanh(y)
  return 0.5f * x * (1.0f + t);
}

__device__ __forceinline__ void gload_lds16(const unsigned short* g, unsigned short* l) {
  __builtin_amdgcn_global_load_lds(
      (__attribute__((address_space(1))) void*)g,
      (__attribute__((address_space(3))) void*)l,
      16, 0, 0);
}

__device__ __forceinline__ bf16x8 lds_read_b128(lds_cus* p) {
  bf16x8 r;
  asm volatile("ds_read_b128 %0, %1" : "=v"(r) : "v"(p));
  return r;
}

// ---- elementwise fp32 -> bf16 convert (x) ----
__global__ void cvt_x_kernel(const float* __restrict__ in, unsigned short* __restrict__ out, int n4) {
  int idx = blockIdx.x * blockDim.x + threadIdx.x;
  int stride = gridDim.x * blockDim.x;
  const float4* in4 = (const float4*)in;
  ushort4* out4 = (ushort4*)out;
  for (int i = idx; i < n4; i += stride) {
    float4 f = in4[i];
    ushort4 o;
    o.x = f2bf(f.x); o.y = f2bf(f.y); o.z = f2bf(f.z); o.w = f2bf(f.w);
    out4[i] = o;
  }
}

// ---- tiled transpose + convert: in fp32 [R][C] per expert -> out bf16 [C][R] ----
__global__ void transpose_cvt_kernel(const float* __restrict__ in, unsigned short* __restrict__ out,
                                     int R, int C) {
  __shared__ float tile[32][33];
  const size_t eoff = (size_t)blockIdx.z * R * C;
  const float* src = in + eoff;
  unsigned short* dst = out + eoff;
  const int c0 = blockIdx.x * 32, r0 = blockIdx.y * 32;
  const int tx = threadIdx.x, ty = threadIdx.y;
#pragma unroll
  for (int i = 0; i < 4; ++i)
    tile[ty + 8 * i][tx] = src[(size_t)(r0 + ty + 8 * i) * C + c0 + tx];
  __syncthreads();
#pragma unroll
  for (int i = 0; i < 4; ++i)
    dst[(size_t)(c0 + ty + 8 * i) * R + r0 + tx] = f2bf(tile[tx][ty + 8 * i]);
}

// ============================================================================
// REAL GEMM body (unchanged from R7): 256x256, BK=64, 8-wave, 4-phase/K-tile.
// ============================================================================
template <int K, int NCOLS, int NTG, bool GELU>
__device__ __forceinline__ void gemm_body(const unsigned short* __restrict__ A,
                                          const unsigned short* __restrict__ Bt,
                                          const float* __restrict__ bias,
                                          unsigned short* __restrict__ OutBf,
                                          float* __restrict__ OutF) {
  constexpr int MT = 2048 / 256;
  constexpr int NTl = NCOLS / 256;
  constexpr int G = NTl / NTG;
  constexpr int NT = K / 64;

  __shared__ __align__(16) unsigned short A0k0[8192], A0k1[8192], B0k0[8192], B0k1[8192];
  __shared__ __align__(16) unsigned short A1k0[8192], A1k1[8192], B1k0[8192], B1k1[8192];

  const int nwg = gridDim.x;
  const int flat = blockIdx.x;
  const int swz = (flat & 7) * (nwg >> 3) + (flat >> 3);
  const int e = swz / (MT * G);
  const int rem = swz - e * (MT * G);
  const int ng = rem / MT;
  const int mt = rem - ng * MT;

  const int m0 = mt * 256;
  const int b = m0 >> 10;
  const int nl = m0 & 1023;
  const size_t arow0 = (size_t)((b * E_ + e) * N_ + nl);

  const unsigned short* Ab = A + arow0 * K;

  const int tid = threadIdx.x;
  const int w = tid >> 6;
  const int lane = tid & 63;
  const int wr = w >> 2;
  const int wc = w & 3;
  const int fr = lane & 15;
  const int kg = lane >> 4;
  const int sxor = kg ^ ((lane >> 1) & 3);

  const int scol = (((lane & 3) ^ ((lane >> 3) & 3)) << 3);
  const int srow0 = w * 32 + (lane >> 2);
  const int srow1 = w * 32 + 16 + (lane >> 2);
  const unsigned short* aS0 = Ab + (size_t)srow0 * K + scol;
  const unsigned short* aS1 = Ab + (size_t)srow1 * K + scol;

  const int aBase = (wr * 128 + fr) * 32 + sxor * 8;
  const int bBase = (wc * 64 + fr) * 32 + sxor * 8;
  const int rb = kg * 4;

#define STAGE(ARR, S0_, S1_, t, kh) do {                           \
    const size_t ko_ = (size_t)(t) * 64 + (kh) * 32;               \
    gload_lds16(S0_ + ko_, &ARR[w * 1024]);                        \
    gload_lds16(S1_ + ko_, &ARR[w * 1024 + 512]);                  \
  } while (0)

#define WAIT_LGKM() do {                                                      \
    asm volatile("s_waitcnt lgkmcnt(0)");                                     \
    __builtin_amdgcn_sched_barrier(0);                                        \
  } while (0)

#define MFMA_CLUSTER(ROFF)                                                    \
    __builtin_amdgcn_s_setprio(1);                                            \
    _Pragma("unroll")                                                         \
    for (int mi = 0; mi < 4; ++mi)                                            \
      _Pragma("unroll")                                                       \
      for (int ni = 0; ni < 4; ++ni)                                          \
        acc[(ROFF) + mi][ni] =                                                \
            __builtin_amdgcn_mfma_f32_16x16x32_bf16(av[mi], bv[ni],           \
                                                    acc[(ROFF) + mi][ni], 0, 0, 0); \
    __builtin_amdgcn_s_setprio(0);

#define ITER(t, CA0, CA1, CB0, CB1, NA1, NB1) do {                            \
    bf16x8 av[4], bv[4];                                                      \
    _Pragma("unroll")                                                         \
    for (int i = 0; i < 4; ++i) {                                             \
      av[i] = lds_read_b128((lds_cus*)&CA0[aBase + i * 512]);                 \
      bv[i] = lds_read_b128((lds_cus*)&CB0[bBase + i * 512]);                 \
    }                                                                         \
    if ((t) + 1 < NT) STAGE(NA1, aS0, aS1, (t) + 1, 1);                       \
    __builtin_amdgcn_s_barrier();                                             \
    WAIT_LGKM();                                                              \
    MFMA_CLUSTER(0)                                                           \
    __builtin_amdgcn_s_barrier();                                             \
    _Pragma("unroll")                                                         \
    for (int i = 0; i < 4; ++i)                                               \
      av[i] = lds_read_b128((lds_cus*)&CA0[aBase + 2048 + i * 512]);          \
    if ((t) + 1 < NT) STAGE(NB1, bS0, bS1, (t) + 1, 1);                       \
    __builtin_amdgcn_s_barrier();                                             \
    WAIT_LGKM();                                                              \
    MFMA_CLUSTER(4)                                                           \
    __builtin_amdgcn_s_barrier();                                             \
    _Pragma("unroll")                                                         \
    for (int i = 0; i < 4; ++i) {                                             \
      av[i] = lds_read_b128((lds_cus*)&CA1[aBase + i * 512]);                 \
      bv[i] = lds_read_b128((lds_cus*)&CB1[bBase + i * 512]);                 \
    }                                                                         \
    if ((t) + 2 < NT) STAGE(CA0, aS0, aS1, (t) + 2, 0);                       \
    __builtin_amdgcn_s_barrier();                                             \
    WAIT_LGKM();                                                              \
    MFMA_CLUSTER(0)                                                           \
    __builtin_amdgcn_s_barrier();                                             \
    _Pragma("unroll")                                                         \
    for (int i = 0; i < 4; ++i)                                               \
      av[i] = lds_read_b128((lds_cus*)&CA1[aBase + 2048 + i * 512]);          \
    if ((t) + 2 < NT) STAGE(CB0, bS0, bS1, (t) + 2, 0);                       \
    __builtin_amdgcn_s_barrier();                                             \
    WAIT_LGKM();                                                              \
    MFMA_CLUSTER(4)                                                           \
    if ((t) + 2 < NT) { asm volatile("s_waitcnt vmcnt(4)" ::: "memory"); }    \
    else              { asm volatile("s_waitcnt vmcnt(0)" ::: "memory"); }    \
    __builtin_amdgcn_s_barrier();                                             \
  } while (0)

#pragma unroll 1
  for (int ig = 0; ig < NTG; ++ig) {
    const int nt = ng * NTG + ig;
    const int n0 = nt * 256;
    const unsigned short* Bb = Bt + ((size_t)e * NCOLS + n0) * K;
    const unsigned short* bS0 = Bb + (size_t)srow0 * K + scol;
    const unsigned short* bS1 = Bb + (size_t)srow1 * K + scol;

    f32x4 acc[8][4];
#pragma unroll
    for (int i = 0; i < 8; ++i)
#pragma unroll
      for (int j = 0; j < 4; ++j)
        acc[i][j] = (f32x4){0.f, 0.f, 0.f, 0.f};

    STAGE(A0k0, aS0, aS1, 0, 0); STAGE(B0k0, bS0, bS1, 0, 0);
    STAGE(A0k1, aS0, aS1, 0, 1); STAGE(B0k1, bS0, bS1, 0, 1);
    STAGE(A1k0, aS0, aS1, 1, 0); STAGE(B1k0, bS0, bS1, 1, 0);
    asm volatile("s_waitcnt vmcnt(4)" ::: "memory");
    __builtin_amdgcn_s_barrier();

#pragma unroll 1
    for (int tt = 0; tt < NT; tt += 2) {
      ITER(tt,     A0k0, A0k1, B0k0, B0k1, A1k1, B1k1);
      ITER(tt + 1, A1k0, A1k1, B1k0, B1k1, A0k1, B0k1);
    }

    if constexpr (GELU) {
      float bval[4];
#pragma unroll
      for (int ni = 0; ni < 4; ++ni)
        bval[ni] = bias[(size_t)e * NCOLS + n0 + wc * 64 + ni * 16 + fr];
      const size_t gcb = (size_t)n0 + wc * 64 + fr;
#pragma unroll
      for (int MI = 0; MI < 8; ++MI) {
#pragma unroll
        for (int j = 0; j < 4; ++j) {
          const size_t orow = arow0 + (size_t)(wr * 128 + MI * 16 + rb + j);
          unsigned short* rp = OutBf + orow * NCOLS + gcb;
#pragma unroll
          for (int ni = 0; ni < 4; ++ni) {
            float v = acc[MI][ni][j] + bval[ni];
            rp[ni * 16] = f2bf(gelu_fast(v));
          }
        }
      }
    } else {
#pragma unroll
      for (int ni = 0; ni < 4; ++ni) {
        const int gc = n0 + wc * 64 + ni * 16 + fr;
        const float bval = bias[(size_t)e * NCOLS + gc];
#pragma unroll
        for (int MI = 0; MI < 8; ++MI) {
          const size_t orow = arow0 + (size_t)(wr * 128 + MI * 16 + rb);
#pragma unroll
          for (int j = 0; j < 4; ++j)
            OutF[(orow + j) * NCOLS + gc] = acc[MI][ni][j] + bval;
        }
      }
    }
  }

#undef ITER
#undef MFMA_CLUSTER
#undef WAIT_LGKM
#undef STAGE
}

__global__ __launch_bounds__(512, 2)
void gemm_mlp1(const unsigned short* __restrict__ A, const unsigned short* __restrict__ Bt,
               const float* __restrict__ bias, unsigned short* __restrict__ OutBf) {
  gemm_body<D_, H_, 4, true>(A, Bt, bias, OutBf, nullptr);
}

__global__ __launch_bounds__(512, 2)
void gemm_mlp2(const unsigned short* __restrict__ A, const unsigned short* __restrict__ Bt,
               const float* __restrict__ bias, float* __restrict__ OutF) {
  gemm_body<H_, D_, 1, false>(A, Bt, bias, nullptr, OutF);
}

// ============================================================================
// ABLATION PROBES (timing-only; write dead scratch = w2t region, dead after
// GEMM2; regenerated by convs each replay). G1 configuration, quarter-work
// (1 n-tile/block, 16 K-tiles), REP internal passes for table visibility.
//   VAR 0: exact G1 clone (bf16+gelu stores, 2KB-stride sources)  -- anchor
//   VAR 1: fp32 stores, no gelu (2x bytes; isolates epilogue path)
//   VAR 2: as VAR0 but sources at 8KB row stride (every-4th-row; isolates
//          the stride hypothesis; same inter-block sharing topology)
// ============================================================================
template <int REP, int VAR>
__global__ __launch_bounds__(512, 2)
void abl_g1(const unsigned short* __restrict__ A,    // xb  [16384][1024]
            const unsigned short* __restrict__ Bt,   // w1t [8][4096][1024]
            const float* __restrict__ bias,          // b1  [8][4096]
            void* __restrict__ OutRaw) {             // 67MB dead scratch
  constexpr int K = 1024;
  constexpr int NT = K / 64;
  constexpr int MT = 8;
  constexpr int G = 4;   // quarter of H n-tile space

  __shared__ __align__(16) unsigned short A0k0[8192], A0k1[8192], B0k0[8192], B0k1[8192];
  __shared__ __align__(16) unsigned short A1k0[8192], A1k1[8192], B1k0[8192], B1k1[8192];

  const int nwg = gridDim.x;
  const int flat = blockIdx.x;
  const int swz = (flat & 7) * (nwg >> 3) + (flat >> 3);
  const int e = swz / (MT * G);
  const int rem = swz - e * (MT * G);
  const int ng = rem / MT;
  const int mt = rem - ng * MT;

  const int m0 = mt * 256;
  const int b = m0 >> 10;
  const int nl = m0 & 1023;
  const size_t arow0 = (size_t)((b * E_ + e) * N_ + nl);
  const int n0 = ng * 256;

  const int tid = threadIdx.x;
  const int w = tid >> 6;
  const int lane = tid & 63;
  const int wr = w >> 2;
  const int wc = w & 3;
  const int fr = lane & 15;
  const int kg = lane >> 4;
  const int sxor = kg ^ ((lane >> 1) & 3);

  const int scol = (((lane & 3) ^ ((lane >> 3) & 3)) << 3);
  const int srow0 = w * 32 + (lane >> 2);
  const int srow1 = w * 32 + 16 + (lane >> 2);

  const unsigned short *aS0, *aS1, *bS0, *bS1;
  if constexpr (VAR == 2) {
    // 8KB row stride: physical row = (tile_row_index)*4 + subslot; distinct
    // per block-group, same sharing topology as the real G1 (A shared by 4
    // ng-blocks, B shared by 8 mt-blocks).
    aS0 = A + ((size_t)(((e & 1) * 2048 + mt * 256 + srow0) * 4 + (e >> 1))) * K + scol;
    aS1 = A + ((size_t)(((e & 1) * 2048 + mt * 256 + srow1) * 4 + (e >> 1))) * K + scol;
    bS0 = Bt + ((size_t)e * H_ + (size_t)(n0 + srow0) * 4) * K + scol;
    bS1 = Bt + ((size_t)e * H_ + (size_t)(n0 + srow1) * 4) * K + scol;
  } else {
    aS0 = A + (arow0 + srow0) * K + scol;
    aS1 = A + (arow0 + srow1) * K + scol;
    bS0 = Bt + ((size_t)e * H_ + n0 + srow0) * K + scol;
    bS1 = Bt + ((size_t)e * H_ + n0 + srow1) * K + scol;
  }

  const int aBase = (wr * 128 + fr) * 32 + sxor * 8;
  const int bBase = (wc * 64 + fr) * 32 + sxor * 8;
  const int rb = kg * 4;

#define STAGE(ARR, S0_, S1_, t, kh) do {                           \
    const size_t ko_ = (size_t)(t) * 64 + (kh) * 32;               \
    gload_lds16(S0_ + ko_, &ARR[w * 1024]);                        \
    gload_lds16(S1_ + ko_, &ARR[w * 1024 + 512]);                  \
  } while (0)

#define WAIT_LGKM() do {                                                      \
    asm volatile("s_waitcnt lgkmcnt(0)");                                     \
    __builtin_amdgcn_sched_barrier(0);                                        \
  } while (0)

#define MFMA_CLUSTER(ROFF)                                                    \
    __builtin_amdgcn_s_setprio(1);                                            \
    _Pragma("unroll")                                                         \
    for (int mi = 0; mi < 4; ++mi)                                            \
      _Pragma("unroll")                                                       \
      for (int ni = 0; ni < 4; ++ni)                                          \
        acc[(ROFF) + mi][ni] =                                                \
            __builtin_amdgcn_mfma_f32_16x16x32_bf16(av[mi], bv[ni],           \
                                                    acc[(ROFF) + mi][ni], 0, 0, 0); \
    __builtin_amdgcn_s_setprio(0);

#define ITER(t, CA0, CA1, CB0, CB1, NA1, NB1) do {                            \
    bf16x8 av[4], bv[4];                                                      \
    _Pragma("unroll")                                                         \
    for (int i = 0; i < 4; ++i) {                                             \
      av[i] = lds_read_b128((lds_cus*)&CA0[aBase + i * 512]);                 \
      bv[i] = lds_read_b128((lds_cus*)&CB0[bBase + i * 512]);                 \
    }                                                                         \
    if ((t) + 1 < NT) STAGE(NA1, aS0, aS1, (t) + 1, 1);                       \
    __builtin_amdgcn_s_barrier();                                             \
    WAIT_LGKM();                                                              \
    MFMA_CLUSTER(0)                                                           \
    __builtin_amdgcn_s_barrier();                                             \
    _Pragma("unroll")                                                         \
    for (int i = 0; i < 4; ++i)                                               \
      av[i] = lds_read_b128((lds_cus*)&CA0[aBase + 2048 + i * 512]);          \
    if ((t) + 1 < NT) STAGE(NB1, bS0, bS1, (t) + 1, 1);                       \
    __builtin_amdgcn_s_barrier();                                             \
    WAIT_LGKM();                                                              \
    MFMA_CLUSTER(4)                                                           \
    __builtin_amdgcn_s_barrier();                                             \
    _Pragma("unroll")                                                         \
    for (int i = 0; i < 4; ++i) {                                             \
      av[i] = lds_read_b128((lds_cus*)&CA1[aBase + i * 512]);                 \
      bv[i] = lds_read_b128((lds_cus*)&CB1[bBase + i * 512]);                 \
    }                                                                         \
    if ((t) + 2 < NT) STAGE(CA0, aS0, aS1, (t) + 2, 0);                       \
    __builtin_amdgcn_s_barrier();                                             \
    WAIT_LGKM();                                                              \
    MFMA_CLUSTER(0)                                                           \
    __builtin_amdgcn_s_barrier();                                             \
    _Pragma("unroll")                                                         \
    for (int i = 0; i < 4; ++i)                                               \
      av[i] = lds_read_b128((lds_cus*)&CA1[aBase + 2048 + i * 512]);          \
    if ((t) + 2 < NT) STAGE(CB0, bS0, bS1, (t) + 2, 0);                       \
    __builtin_amdgcn_s_barrier();                                             \
    WAIT_LGKM();                                                              \
    MFMA_CLUSTER(4)                                                           \
    if ((t) + 2 < NT) { asm volatile("s_waitcnt vmcnt(4)" ::: "memory"); }    \
    else              { asm volatile("s_waitcnt vmcnt(0)" ::: "memory"); }    \
    __builtin_amdgcn_s_barrier();                                             \
  } while (0)

#pragma unroll 1
  for (int rep = 0; rep < REP; ++rep) {
    f32x4 acc[8][4];
#pragma unroll
    for (int i = 0; i < 8; ++i)
#pragma unroll
      for (int j = 0; j < 4; ++j)
        acc[i][j] = (f32x4){0.f, 0.f, 0.f, 0.f};

    STAGE(A0k0, aS0, aS1, 0, 0); STAGE(B0k0, bS0, bS1, 0, 0);
    STAGE(A0k1, aS0, aS1, 0, 1); STAGE(B0k1, bS0, bS1, 0, 1);
    STAGE(A1k0, aS0, aS1, 1, 0); STAGE(B1k0, bS0, bS1, 1, 0);
    asm volatile("s_waitcnt vmcnt(4)" ::: "memory");
    __builtin_amdgcn_s_barrier();

#pragma unroll 1
    for (int tt = 0; tt < NT; tt += 2) {
      ITER(tt,     A0k0, A0k1, B0k0, B0k1, A1k1, B1k1);
      ITER(tt + 1, A1k0, A1k1, B1k0, B1k1, A0k1, B0k1);
    }

    if constexpr (VAR != 1) {
      unsigned short* Out = (unsigned short*)OutRaw;
      float bval[4];
#pragma unroll
      for (int ni = 0; ni < 4; ++ni)
        bval[ni] = bias[(size_t)e * H_ + n0 + wc * 64 + ni * 16 + fr];
      const size_t gcb = (size_t)n0 + wc * 64 + fr;
#pragma unroll
      for (int MI = 0; MI < 8; ++MI) {
#pragma unroll
        for (int j = 0; j < 4; ++j) {
          const size_t orow = arow0 + (size_t)(wr * 128 + MI * 16 + rb + j);
          unsigned short* rp = Out + orow * 1024 + gcb;
#pragma unroll
          for (int ni = 0; ni < 4; ++ni) {
            float v = acc[MI][ni][j] + bval[ni];
            rp[ni * 16] = f2bf(gelu_fast(v));
          }
        }
      }
    } else {
      float* Out = (float*)OutRaw;
#pragma unroll
      for (int ni = 0; ni < 4; ++ni) {
        const int gc = n0 + wc * 64 + ni * 16 + fr;
        const float bval = bias[(size_t)e * H_ + gc];
#pragma unroll
        for (int MI = 0; MI < 8; ++MI) {
          const size_t orow = arow0 + (size_t)(wr * 128 + MI * 16 + rb);
#pragma unroll
          for (int j = 0; j < 4; ++j)
            Out[(orow + j) * 1024 + (gc & 1023)] = acc[MI][ni][j] + bval;
        }
      }
    }
  }

#undef ITER
#undef MFMA_CLUSTER
#undef WAIT_LGKM
#undef STAGE
}

extern "C" void kernel_launch(void* const* d_in, const int* in_sizes, int n_in,
                              void* d_out, int out_size, void* d_ws, size_t ws_size,
                              hipStream_t stream) {
  const float* x  = (const float*)d_in[0];
  const float* w1 = (const float*)d_in[1];
  const float* b1 = (const float*)d_in[2];
  const float* w2 = (const float*)d_in[3];
  const float* b2 = (const float*)d_in[4];
  float* out = (float*)d_out;

  const size_t xN  = (size_t)B_ * E_ * N_ * D_;
  const size_t w1N = (size_t)E_ * D_ * H_;
  const size_t w2N = (size_t)E_ * H_ * D_;
  const size_t hN  = (size_t)B_ * E_ * N_ * H_;
  const size_t needed = (xN + w1N + w2N + hN) * 2;
  if (ws_size < needed) return;

  unsigned short* xb  = (unsigned short*)d_ws;
  unsigned short* w1t = xb + xN;   // [E][H][D] bf16
  unsigned short* w2t = w1t + w1N; // [E][D][H] bf16
  unsigned short* hb  = w2t + w2N; // [B][E][N][H] bf16

  dim3 tb(32, 8);
  transpose_cvt_kernel<<<dim3(D_ / 32, H_ / 32, E_), tb, 0, stream>>>(w2, w2t, H_, D_);
  transpose_cvt_kernel<<<dim3(H_ / 32, D_ / 32, E_), tb, 0, stream>>>(w1, w1t, D_, H_);
  cvt_x_kernel<<<2048, 256, 0, stream>>>(x, xb, (int)(xN / 4));

  gemm_mlp1<<<E_ * 8 * (H_ / 256 / 4), 512, 0, stream>>>(xb, w1t, b1, hb);
  gemm_mlp2<<<E_ * 8 * (D_ / 256), 512, 0, stream>>>(hb, w2t, b2, out);

  // Diagnostic probes (after real GEMMs; w2t is dead here and is regenerated
  // by the transpose kernels on the next replay; d_out unaffected).
  abl_g1<6, 0><<<256, 512, 0, stream>>>(xb, w1t, b1, (void*)w2t);
  abl_g1<10, 1><<<256, 512, 0, stream>>>(xb, w1t, b1, (void*)w2t);
  abl_g1<12, 2><<<256, 512, 0, stream>>>(xb, w1t, b1, (void*)w2t);
}

// Round 9
// 448.443 us; speedup vs baseline: 5.7150x; 5.7150x over previous
//
#include <hip/hip_runtime.h>
#include <stdint.h>

#define B_ 2
#define E_ 8
#define N_ 1024
#define D_ 1024
#define H_ 4096

typedef float f32x4 __attribute__((ext_vector_type(4)));
typedef __bf16 bf16x8 __attribute__((ext_vector_type(8)));
typedef __attribute__((address_space(3))) const unsigned short lds_cus;

__device__ __forceinline__ unsigned short f2bf(float f) {
  union { float f; uint32_t u; } v; v.f = f;
  uint32_t u = v.u;
  return (unsigned short)((u + 0x7FFFu + ((u >> 16) & 1u)) >> 16);  // RNE
}

// tanh-form GELU (max |delta| vs exact erf-GELU ~1e-3, inside threshold headroom)
__device__ __forceinline__ float gelu_fast(float x) {
  float x3 = x * x * x;
  float y = 0.79788456080286536f * (x + 0.044715f * x3);
  float e = __expf(2.0f * y);
  float t = 1.0f - 2.0f / (e + 1.0f);   // tanh(y)
  return 0.5f * x * (1.0f + t);
}

__device__ __forceinline__ void gload_lds16(const unsigned short* g, unsigned short* l) {
  __builtin_amdgcn_global_load_lds(
      (__attribute__((address_space(1))) void*)g,
      (__attribute__((address_space(3))) void*)l,
      16, 0, 0);
}

__device__ __forceinline__ bf16x8 lds_read_b128(lds_cus* p) {
  bf16x8 r;
  asm volatile("ds_read_b128 %0, %1" : "=v"(r) : "v"(p));
  return r;
}

// ---- elementwise fp32 -> bf16 convert (x) ----
__global__ void cvt_x_kernel(const float* __restrict__ in, unsigned short* __restrict__ out, int n4) {
  int idx = blockIdx.x * blockDim.x + threadIdx.x;
  int stride = gridDim.x * blockDim.x;
  const float4* in4 = (const float4*)in;
  ushort4* out4 = (ushort4*)out;
  for (int i = idx; i < n4; i += stride) {
    float4 f = in4[i];
    ushort4 o;
    o.x = f2bf(f.x); o.y = f2bf(f.y); o.z = f2bf(f.z); o.w = f2bf(f.w);
    out4[i] = o;
  }
}

// ---- tiled transpose + convert: in fp32 [R][C] per expert -> out bf16 [C][R] ----
__global__ void transpose_cvt_kernel(const float* __restrict__ in, unsigned short* __restrict__ out,
                                     int R, int C) {
  __shared__ float tile[32][33];
  const size_t eoff = (size_t)blockIdx.z * R * C;
  const float* src = in + eoff;
  unsigned short* dst = out + eoff;
  const int c0 = blockIdx.x * 32, r0 = blockIdx.y * 32;
  const int tx = threadIdx.x, ty = threadIdx.y;
#pragma unroll
  for (int i = 0; i < 4; ++i)
    tile[ty + 8 * i][tx] = src[(size_t)(r0 + ty + 8 * i) * C + c0 + tx];
  __syncthreads();
#pragma unroll
  for (int i = 0; i < 4; ++i)
    dst[(size_t)(c0 + ty + 8 * i) * R + r0 + tx] = f2bf(tile[tx][ty + 8 * i]);
}

// ============================================================================
// 256x256-tile, BK=64, 8-wave, 4-phase/K-tile bf16 MFMA GEMM (R4 schedule,
// R6 NTG grouping, R7 store-friendly epilogue).
// R9: GELU epilogue repacks the 256x256 bf16 output tile through LDS
// (row pad +8 elems => <=2-way write conflicts (free), conflict-free b128
// reads) and stores via dwordx4: 512B contiguous per row per instruction,
// 16 store instrs/thread/ig instead of 128 x 2B scalar stores.
// LDS: single 135,168B array; staging uses the first 128KB (8 x 8192-elem
// slots); epilogue reuses the whole array after the K-loop drain barrier.
// ============================================================================
template <int K, int NCOLS, int NTG, bool GELU>
__device__ __forceinline__ void gemm_body(const unsigned short* __restrict__ A,
                                          const unsigned short* __restrict__ Bt,
                                          const float* __restrict__ bias,
                                          unsigned short* __restrict__ OutBf,
                                          float* __restrict__ OutF) {
  constexpr int MT = 2048 / 256;
  constexpr int NTl = NCOLS / 256;
  constexpr int G = NTl / NTG;
  constexpr int NT = K / 64;
  constexpr int EPI_LD = 264;  // 256 + 8 pad (elements)

  __shared__ __align__(16) unsigned short LDSU[256 * EPI_LD];  // 135,168 B
  unsigned short* const A0k0 = LDSU;
  unsigned short* const A0k1 = LDSU + 8192;
  unsigned short* const B0k0 = LDSU + 16384;
  unsigned short* const B0k1 = LDSU + 24576;
  unsigned short* const A1k0 = LDSU + 32768;
  unsigned short* const A1k1 = LDSU + 40960;
  unsigned short* const B1k0 = LDSU + 49152;
  unsigned short* const B1k1 = LDSU + 57344;

  const int nwg = gridDim.x;
  const int flat = blockIdx.x;
  const int swz = (flat & 7) * (nwg >> 3) + (flat >> 3);
  const int e = swz / (MT * G);
  const int rem = swz - e * (MT * G);
  const int ng = rem / MT;
  const int mt = rem - ng * MT;

  const int m0 = mt * 256;
  const int b = m0 >> 10;
  const int nl = m0 & 1023;
  const size_t arow0 = (size_t)((b * E_ + e) * N_ + nl);

  const unsigned short* Ab = A + arow0 * K;

  const int tid = threadIdx.x;
  const int w = tid >> 6;
  const int lane = tid & 63;
  const int wr = w >> 2;
  const int wc = w & 3;
  const int fr = lane & 15;
  const int kg = lane >> 4;
  const int sxor = kg ^ ((lane >> 1) & 3);

  const int scol = (((lane & 3) ^ ((lane >> 3) & 3)) << 3);
  const int srow0 = w * 32 + (lane >> 2);
  const int srow1 = w * 32 + 16 + (lane >> 2);
  const unsigned short* aS0 = Ab + (size_t)srow0 * K + scol;
  const unsigned short* aS1 = Ab + (size_t)srow1 * K + scol;

  const int aBase = (wr * 128 + fr) * 32 + sxor * 8;
  const int bBase = (wc * 64 + fr) * 32 + sxor * 8;
  const int rb = kg * 4;

#define STAGE(ARR, S0_, S1_, t, kh) do {                           \
    const size_t ko_ = (size_t)(t) * 64 + (kh) * 32;               \
    gload_lds16(S0_ + ko_, &ARR[w * 1024]);                        \
    gload_lds16(S1_ + ko_, &ARR[w * 1024 + 512]);                  \
  } while (0)

#define WAIT_LGKM() do {                                                      \
    asm volatile("s_waitcnt lgkmcnt(0)");                                     \
    __builtin_amdgcn_sched_barrier(0);                                        \
  } while (0)

#define MFMA_CLUSTER(ROFF)                                                    \
    __builtin_amdgcn_s_setprio(1);                                            \
    _Pragma("unroll")                                                         \
    for (int mi = 0; mi < 4; ++mi)                                            \
      _Pragma("unroll")                                                       \
      for (int ni = 0; ni < 4; ++ni)                                          \
        acc[(ROFF) + mi][ni] =                                                \
            __builtin_amdgcn_mfma_f32_16x16x32_bf16(av[mi], bv[ni],           \
                                                    acc[(ROFF) + mi][ni], 0, 0, 0); \
    __builtin_amdgcn_s_setprio(0);

#define ITER(t, CA0, CA1, CB0, CB1, NA1, NB1) do {                            \
    bf16x8 av[4], bv[4];                                                      \
    _Pragma("unroll")                                                         \
    for (int i = 0; i < 4; ++i) {                                             \
      av[i] = lds_read_b128((lds_cus*)&CA0[aBase + i * 512]);                 \
      bv[i] = lds_read_b128((lds_cus*)&CB0[bBase + i * 512]);                 \
    }                                                                         \
    if ((t) + 1 < NT) STAGE(NA1, aS0, aS1, (t) + 1, 1);                       \
    __builtin_amdgcn_s_barrier();                                             \
    WAIT_LGKM();                                                              \
    MFMA_CLUSTER(0)                                                           \
    __builtin_amdgcn_s_barrier();                                             \
    _Pragma("unroll")                                                         \
    for (int i = 0; i < 4; ++i)                                               \
      av[i] = lds_read_b128((lds_cus*)&CA0[aBase + 2048 + i * 512]);          \
    if ((t) + 1 < NT) STAGE(NB1, bS0, bS1, (t) + 1, 1);                       \
    __builtin_amdgcn_s_barrier();                                             \
    WAIT_LGKM();                                                              \
    MFMA_CLUSTER(4)                                                           \
    __builtin_amdgcn_s_barrier();                                             \
    _Pragma("unroll")                                                         \
    for (int i = 0; i < 4; ++i) {                                             \
      av[i] = lds_read_b128((lds_cus*)&CA1[aBase + i * 512]);                 \
      bv[i] = lds_read_b128((lds_cus*)&CB1[bBase + i * 512]);                 \
    }                                                                         \
    if ((t) + 2 < NT) STAGE(CA0, aS0, aS1, (t) + 2, 0);                       \
    __builtin_amdgcn_s_barrier();                                             \
    WAIT_LGKM();                                                              \
    MFMA_CLUSTER(0)                                                           \
    __builtin_amdgcn_s_barrier();                                             \
    _Pragma("unroll")                                                         \
    for (int i = 0; i < 4; ++i)                                               \
      av[i] = lds_read_b128((lds_cus*)&CA1[aBase + 2048 + i * 512]);          \
    if ((t) + 2 < NT) STAGE(CB0, bS0, bS1, (t) + 2, 0);                       \
    __builtin_amdgcn_s_barrier();                                             \
    WAIT_LGKM();                                                              \
    MFMA_CLUSTER(4)                                                           \
    if ((t) + 2 < NT) { asm volatile("s_waitcnt vmcnt(4)" ::: "memory"); }    \
    else              { asm volatile("s_waitcnt vmcnt(0)" ::: "memory"); }    \
    __builtin_amdgcn_s_barrier();                                             \
  } while (0)

#pragma unroll 1
  for (int ig = 0; ig < NTG; ++ig) {
    const int nt = ng * NTG + ig;
    const int n0 = nt * 256;
    const unsigned short* Bb = Bt + ((size_t)e * NCOLS + n0) * K;
    const unsigned short* bS0 = Bb + (size_t)srow0 * K + scol;
    const unsigned short* bS1 = Bb + (size_t)srow1 * K + scol;

    f32x4 acc[8][4];
#pragma unroll
    for (int i = 0; i < 8; ++i)
#pragma unroll
      for (int j = 0; j < 4; ++j)
        acc[i][j] = (f32x4){0.f, 0.f, 0.f, 0.f};

    STAGE(A0k0, aS0, aS1, 0, 0); STAGE(B0k0, bS0, bS1, 0, 0);
    STAGE(A0k1, aS0, aS1, 0, 1); STAGE(B0k1, bS0, bS1, 0, 1);
    STAGE(A1k0, aS0, aS1, 1, 0); STAGE(B1k0, bS0, bS1, 1, 0);
    asm volatile("s_waitcnt vmcnt(4)" ::: "memory");
    __builtin_amdgcn_s_barrier();

#pragma unroll 1
    for (int tt = 0; tt < NT; tt += 2) {
      ITER(tt,     A0k0, A0k1, B0k0, B0k1, A1k1, B1k1);
      ITER(tt + 1, A1k0, A1k1, B1k0, B1k1, A0k1, B0k1);
    }

    if constexpr (GELU) {
      // -------- R9 epilogue: LDS repack -> dwordx4 streaming stores --------
      // Phase 1: each thread drops its 128 bf16 results into the [256][264]
      // LDS tile at true (row,col). Write conflicts <=2-way (row pad).
      float bval[4];
#pragma unroll
      for (int ni = 0; ni < 4; ++ni)
        bval[ni] = bias[(size_t)e * NCOLS + n0 + wc * 64 + ni * 16 + fr];
#pragma unroll
      for (int MI = 0; MI < 8; ++MI) {
#pragma unroll
        for (int j = 0; j < 4; ++j) {
          const int row = wr * 128 + MI * 16 + rb + j;
#pragma unroll
          for (int ni = 0; ni < 4; ++ni) {
            const int col = wc * 64 + ni * 16 + fr;
            LDSU[row * EPI_LD + col] = f2bf(gelu_fast(acc[MI][ni][j] + bval[ni]));
          }
        }
      }
      __syncthreads();
      // Phase 2: wave w streams rows [w*32, w*32+32). Per instruction:
      // lanes 0-31 cover one full row (32 x 16B = 512B contiguous),
      // lanes 32-63 the next row. 16 b128 LDS reads + 16 dwordx4 stores.
      const int l5 = lane >> 5, l31 = lane & 31;
#pragma unroll
      for (int i = 0; i < 16; ++i) {
        const int row = w * 32 + l5 + i * 2;
        bf16x8 vv = *(const bf16x8*)&LDSU[row * EPI_LD + l31 * 8];
        *(bf16x8*)&OutBf[(arow0 + row) * NCOLS + n0 + l31 * 8] = vv;
      }
      __syncthreads();  // LDS reads drained before next ig's staging overwrites
    } else {
#pragma unroll
      for (int ni = 0; ni < 4; ++ni) {
        const int gc = n0 + wc * 64 + ni * 16 + fr;
        const float bval = bias[(size_t)e * NCOLS + gc];
#pragma unroll
        for (int MI = 0; MI < 8; ++MI) {
          const size_t orow = arow0 + (size_t)(wr * 128 + MI * 16 + rb);
#pragma unroll
          for (int j = 0; j < 4; ++j)
            OutF[(orow + j) * NCOLS + gc] = acc[MI][ni][j] + bval;
        }
      }
    }
  }

#undef ITER
#undef MFMA_CLUSTER
#undef WAIT_LGKM
#undef STAGE
}

__global__ __launch_bounds__(512, 2)
void gemm_mlp1(const unsigned short* __restrict__ A, const unsigned short* __restrict__ Bt,
               const float* __restrict__ bias, unsigned short* __restrict__ OutBf) {
  gemm_body<D_, H_, 4, true>(A, Bt, bias, OutBf, nullptr);
}

__global__ __launch_bounds__(512, 2)
void gemm_mlp2(const unsigned short* __restrict__ A, const unsigned short* __restrict__ Bt,
               const float* __restrict__ bias, float* __restrict__ OutF) {
  gemm_body<H_, D_, 1, false>(A, Bt, bias, nullptr, OutF);
}

extern "C" void kernel_launch(void* const* d_in, const int* in_sizes, int n_in,
                              void* d_out, int out_size, void* d_ws, size_t ws_size,
                              hipStream_t stream) {
  const float* x  = (const float*)d_in[0];
  const float* w1 = (const float*)d_in[1];
  const float* b1 = (const float*)d_in[2];
  const float* w2 = (const float*)d_in[3];
  const float* b2 = (const float*)d_in[4];
  float* out = (float*)d_out;

  const size_t xN  = (size_t)B_ * E_ * N_ * D_;
  const size_t w1N = (size_t)E_ * D_ * H_;
  const size_t w2N = (size_t)E_ * H_ * D_;
  const size_t hN  = (size_t)B_ * E_ * N_ * H_;
  const size_t needed = (xN + w1N + w2N + hN) * 2;
  if (ws_size < needed) return;

  unsigned short* xb  = (unsigned short*)d_ws;
  unsigned short* w1t = xb + xN;   // [E][H][D] bf16
  unsigned short* w2t = w1t + w1N; // [E][D][H] bf16
  unsigned short* hb  = w2t + w2N; // [B][E][N][H] bf16

  dim3 tb(32, 8);
  transpose_cvt_kernel<<<dim3(D_ / 32, H_ / 32, E_), tb, 0, stream>>>(w2, w2t, H_, D_);
  transpose_cvt_kernel<<<dim3(H_ / 32, D_ / 32, E_), tb, 0, stream>>>(w1, w1t, D_, H_);
  cvt_x_kernel<<<2048, 256, 0, stream>>>(x, xb, (int)(xN / 4));

  gemm_mlp1<<<E_ * 8 * (H_ / 256 / 4), 512, 0, stream>>>(xb, w1t, b1, hb);
  gemm_mlp2<<<E_ * 8 * (D_ / 256), 512, 0, stream>>>(hb, w2t, b2, out);
}